// Round 10
// baseline (300.527 us; speedup 1.0000x reference)
//
#include <hip/hip_runtime.h>

#define BSZ 4
#define CIN 64
#define HH 128
#define WW 128
#define OCH 64
#define HWSZ (HH*WW)
#define KK 9
#define NPIX (BSZ*HH*WW)

typedef __attribute__((ext_vector_type(8))) short short8v;
typedef __attribute__((ext_vector_type(4))) float float4v;

// ws layout (float offsets)
#define Y_OFF     0
#define OFFS_OFF  (BSZ*OCH*HWSZ)                   // 4194304; [b][ho][wo][20] = 1310720 floats
#define WOFF2_OFF (OFFS_OFF + BSZ*HWSZ*20)         // 5505024; 10368 floats
#define WTB_OFF   (WOFF2_OFF + 576*18)             // 5515392; 36864 bf16 = 18432 float slots
#define STATS_OFF (WTB_OFF + 18432)                // 5533824; gsum[64] gsq[64] ss[128]

__device__ __forceinline__ short f2bf(float f) {
    unsigned u = __builtin_bit_cast(unsigned, f);
    unsigned r = (u + 0x7FFFu + ((u >> 16) & 1u)) >> 16;
    return (short)r;
}

// ---------------- kernel 0: weight prep ----------------
__global__ void prep_w(const float* __restrict__ w_def,
                       const float* __restrict__ w_off,
                       short* __restrict__ wtb,      // [k][oc][c] bf16
                       float* __restrict__ wof2) {   // [tap][c][18]
    int i = blockIdx.x * 256 + threadIdx.x;
    if (i < 36864) {
        int oc = i / 576, rr = i % 576;
        int c = rr / 9, k = rr % 9;
        wtb[(k * OCH + oc) * CIN + c] = f2bf(w_def[i]);
    } else if (i < 36864 + 10368) {
        int j = i - 36864;
        int o = j / 576, rr = j % 576;
        int c = rr / 9, tap = rr % 9;
        wof2[(tap * CIN + c) * 18 + o] = w_off[j];
    }
}

// ---------------- kernel 1: x NCHW -> NHWC via LDS tile (both sides coalesced) ----------------
// grid 2048 blocks, 32 px per block. XCD-swizzled: XCD j handles a contiguous px band.
__global__ __launch_bounds__(256, 8) void transpose_x(const float* __restrict__ x,
                                                      float* __restrict__ xt) {
    __shared__ float t[64][33];
    const int bid = blockIdx.x;
    const int wg  = (bid & 7) * 256 + (bid >> 3);   // 2048/8 = 256 per XCD
    const int tid = threadIdx.x;
    const int gp0 = wg * 32;                         // b*16384 + hw0
    const int b   = gp0 >> 14;
    const int hw0 = gp0 & 16383;
    const float* src = x + b * CIN * HWSZ + hw0;
    #pragma unroll
    for (int pass = 0; pass < 8; ++pass) {
        int c = pass * 8 + (tid >> 5);
        int p = tid & 31;
        t[c][p] = src[c * HWSZ + p];
    }
    __syncthreads();
    float* dst = xt + (b * HWSZ + hw0) * 64;
    #pragma unroll
    for (int pass = 0; pass < 8; ++pass) {
        int p = pass * 4 + (tid >> 6);
        int c = tid & 63;
        dst[p * 64 + c] = t[c][p];
    }
}

// ---------------- kernel 2: 3x3 offset conv (NHWC reads, 4 blocks/CU) ----------------
// grid 1024: wg>>1 = row id, wg&1 = half-row. 4 waves: og = w&1, c-half = w>>1.
__global__ __launch_bounds__(256, 4) void offset_conv(
    const float* __restrict__ xt,
    const float* __restrict__ b_off,
    const float* __restrict__ wof2,
    float* __restrict__ offs)   // [b][ho][wo][20]
{
    __shared__ float part[2][9][64];   // q2==1 partials: [og][j][px]
    const int bid = blockIdx.x;
    const int wg  = (bid & 7) * 128 + (bid >> 3);   // 1024/8 = 128 per XCD
    const int tid = threadIdx.x;
    const int lane = tid & 63;
    const int wvv = __builtin_amdgcn_readfirstlane(tid >> 6);
    const int og  = wvv & 1;
    const int q2  = wvv >> 1;
    const int row = wg >> 1, half = wg & 1;
    const int b = row >> 7, ho = row & 127;
    const int px = half * 64 + lane;

    float oacc[9];
    #pragma unroll
    for (int j = 0; j < 9; ++j) oacc[j] = (q2 == 0) ? b_off[og * 9 + j] : 0.f;

    const float* xb = xt + b * HWSZ * 64;
    #pragma unroll
    for (int tap = 0; tap < 9; ++tap) {
        const int kh = tap / 3, kw = tap % 3;
        const int yy = ho - 1 + kh;
        const int xx = px - 1 + kw;
        if (((unsigned)yy < (unsigned)HH) & ((unsigned)xx < (unsigned)WW)) {
            const float* pv = xb + (yy * WW + xx) * 64 + q2 * 32;
            const float* wp = wof2 + (tap * CIN + q2 * 32) * 18 + og * 9;
            #pragma unroll
            for (int c8 = 0; c8 < 8; ++c8) {
                float4 xv = *(const float4*)(pv + c8 * 4);
                #pragma unroll
                for (int cc = 0; cc < 4; ++cc) {
                    const float* w = wp + (c8 * 4 + cc) * 18;
                    float xs = (cc == 0) ? xv.x : (cc == 1) ? xv.y : (cc == 2) ? xv.z : xv.w;
                    #pragma unroll
                    for (int j = 0; j < 9; ++j) oacc[j] = fmaf(xs, w[j], oacc[j]);
                }
            }
        }
    }
    if (q2 == 1) {
        #pragma unroll
        for (int j = 0; j < 9; ++j) part[og][j][lane] = oacc[j];
    }
    __syncthreads();
    if (q2 == 0) {
        float* orow = offs + ((b * HH + ho) * WW + px) * 20 + og * 9;
        #pragma unroll
        for (int j = 0; j < 9; ++j) orow[j] = oacc[j] + part[og][j][lane];
    }
}

// ---------------- kernel 3: deform conv via MFMA (NHWC gathers, XCD-local) ----------------
__global__ __launch_bounds__(256, 4) void deform_mfma(
    const float* __restrict__ xt,     // NHWC
    const float* __restrict__ offs,   // [b][ho][wo][20]
    const short* __restrict__ wtb,
    const float* __restrict__ b_def,
    float* __restrict__ ybuf,
    float* __restrict__ gsum,
    float* __restrict__ gsq)
{
    __shared__ float red0[4][64];
    __shared__ float red1[4][64];

    const int bid  = blockIdx.x;
    const int r    = (bid & 7) * 128 + (bid >> 3);   // XCD swizzle, 1024/8 = 128
    const int tid  = threadIdx.x;
    const int lane = tid & 63;
    const int wv   = tid >> 6;
    const int b    = r >> 8;
    const int rem  = r & 255;
    const int ho   = rem >> 1, half = rem & 1;
    const int l15  = lane & 15;
    const int l4   = lane >> 4;
    const int cbase = l4 * 8;
    const int p    = half * 64 + wv * 16 + l15;   // this lane's pixel

    float4v acc[4];
    #pragma unroll
    for (int mt = 0; mt < 4; ++mt) acc[mt] = (float4v){0.f, 0.f, 0.f, 0.f};

    const float* xb = xt + b * HWSZ * 64;

    // hoist all 18 offsets for this pixel (5 vector loads, issued together)
    float och[18];
    {
        const float* op = offs + ((b * HH + ho) * WW + p) * 20;
        float4 o0 = *(const float4*)(op);
        float4 o1 = *(const float4*)(op + 4);
        float4 o2 = *(const float4*)(op + 8);
        float4 o3 = *(const float4*)(op + 12);
        float4 o4 = *(const float4*)(op + 16);
        och[0]=o0.x; och[1]=o0.y; och[2]=o0.z; och[3]=o0.w;
        och[4]=o1.x; och[5]=o1.y; och[6]=o1.z; och[7]=o1.w;
        och[8]=o2.x; och[9]=o2.y; och[10]=o2.z; och[11]=o2.w;
        och[12]=o3.x; och[13]=o3.y; och[14]=o3.z; och[15]=o3.w;
        och[16]=o4.x; och[17]=o4.y;
    }

    #pragma unroll
    for (int k = 0; k < KK; ++k) {
        float dy = och[2 * k];
        float dx = och[2 * k + 1];
        float py = (float)(ho - 1 + (k / 3)) + dy;
        float px = (float)(p - 1 + (k % 3)) + dx;
        float y0f = floorf(py), x0f = floorf(px);
        int y0 = (int)y0f, x0 = (int)x0f;
        float wy1 = py - y0f, wy0 = 1.f - wy1;
        float wx1 = px - x0f, wx0 = 1.f - wx1;
        int vy0 = ((unsigned)y0 < (unsigned)HH), vy1 = ((unsigned)(y0 + 1) < (unsigned)HH);
        int vx0 = ((unsigned)x0 < (unsigned)WW), vx1 = ((unsigned)(x0 + 1) < (unsigned)WW);
        float w00 = wy0 * wx0 * (float)(vy0 & vx0);
        float w01 = wy0 * wx1 * (float)(vy0 & vx1);
        float w10 = wy1 * wx0 * (float)(vy1 & vx0);
        float w11 = wy1 * wx1 * (float)(vy1 & vx1);
        int y0c = min(max(y0, 0), HH - 1), y1c = min(max(y0 + 1, 0), HH - 1);
        int x0c = min(max(x0, 0), WW - 1), x1c = min(max(x0 + 1, 0), WW - 1);
        const float* p00 = xb + (y0c * WW + x0c) * 64;
        const float* p01 = xb + (y0c * WW + x1c) * 64;
        const float* p10 = xb + (y1c * WW + x0c) * 64;
        const float* p11 = xb + (y1c * WW + x1c) * 64;

        short8v Bf[2];
        #pragma unroll
        for (int kc = 0; kc < 2; ++kc) {
            const int co = kc * 32 + cbase;
            float4 a00 = *(const float4*)(p00 + co), b00 = *(const float4*)(p00 + co + 4);
            float4 a01 = *(const float4*)(p01 + co), b01 = *(const float4*)(p01 + co + 4);
            float4 a10 = *(const float4*)(p10 + co), b10 = *(const float4*)(p10 + co + 4);
            float4 a11 = *(const float4*)(p11 + co), b11 = *(const float4*)(p11 + co + 4);
            float v0 = a00.x * w00 + a01.x * w01 + a10.x * w10 + a11.x * w11;
            float v1 = a00.y * w00 + a01.y * w01 + a10.y * w10 + a11.y * w11;
            float v2 = a00.z * w00 + a01.z * w01 + a10.z * w10 + a11.z * w11;
            float v3 = a00.w * w00 + a01.w * w01 + a10.w * w10 + a11.w * w11;
            float v4 = b00.x * w00 + b01.x * w01 + b10.x * w10 + b11.x * w11;
            float v5 = b00.y * w00 + b01.y * w01 + b10.y * w10 + b11.y * w11;
            float v6 = b00.z * w00 + b01.z * w01 + b10.z * w10 + b11.z * w11;
            float v7 = b00.w * w00 + b01.w * w01 + b10.w * w10 + b11.w * w11;
            short8v bf;
            bf[0] = f2bf(v0); bf[1] = f2bf(v1); bf[2] = f2bf(v2); bf[3] = f2bf(v3);
            bf[4] = f2bf(v4); bf[5] = f2bf(v5); bf[6] = f2bf(v6); bf[7] = f2bf(v7);
            Bf[kc] = bf;
        }

        const short* wk = wtb + k * OCH * CIN;
        #pragma unroll
        for (int mt = 0; mt < 4; ++mt) {
            const short* wrow = wk + (mt * 16 + l15) * CIN + cbase;
            #pragma unroll
            for (int kc = 0; kc < 2; ++kc) {
                short8v Af = *(const short8v*)(wrow + kc * 32);
                acc[mt] = __builtin_amdgcn_mfma_f32_16x16x32_bf16(Af, Bf[kc], acc[mt], 0, 0, 0);
            }
        }
    }

    // ---- epilogue: bias, y store, BN partials ----
    // C/D layout: col(pix)=lane&15, row(oc)=(lane>>4)*4+reg
    float lsum[4][4], lsq[4][4];
    const int yrow = ho * WW;
    #pragma unroll
    for (int mt = 0; mt < 4; ++mt) {
        #pragma unroll
        for (int rr = 0; rr < 4; ++rr) {
            const int oc = mt * 16 + l4 * 4 + rr;
            float v = acc[mt][rr] + b_def[oc];
            ybuf[(b * OCH + oc) * HWSZ + yrow + p] = v;
            lsum[mt][rr] = v;
            lsq[mt][rr]  = v * v;
        }
    }
    #pragma unroll
    for (int m = 1; m <= 8; m <<= 1) {
        #pragma unroll
        for (int mt = 0; mt < 4; ++mt)
            #pragma unroll
            for (int rr = 0; rr < 4; ++rr) {
                lsum[mt][rr] += __shfl_xor(lsum[mt][rr], m);
                lsq[mt][rr]  += __shfl_xor(lsq[mt][rr], m);
            }
    }
    if (l15 == 0) {
        #pragma unroll
        for (int mt = 0; mt < 4; ++mt)
            #pragma unroll
            for (int rr = 0; rr < 4; ++rr) {
                const int oc = mt * 16 + l4 * 4 + rr;
                red0[wv][oc] = lsum[mt][rr];
                red1[wv][oc] = lsq[mt][rr];
            }
    }
    __syncthreads();
    if (tid < 128) {
        const int oc = tid & 63, s = tid >> 6;
        if (s == 0) {
            float v = red0[0][oc] + red0[1][oc] + red0[2][oc] + red0[3][oc];
            atomicAdd(&gsum[oc], v);
        } else {
            float v = red1[0][oc] + red1[1][oc] + red1[2][oc] + red1[3][oc];
            atomicAdd(&gsq[oc], v);
        }
    }
}

// ---------------- kernel 4: BN stats finalize ----------------
__global__ void finalize_bn(const float* __restrict__ gsum, const float* __restrict__ gsq,
                            const float* __restrict__ gamma, const float* __restrict__ beta,
                            float* __restrict__ ss) {
    int c = threadIdx.x;
    if (c < OCH) {
        const float inv = 1.f / (float)NPIX;
        float mean = gsum[c] * inv;
        float var = gsq[c] * inv - mean * mean;
        float rstd = rsqrtf(var + 1e-5f);
        float sc = gamma[c] * rstd;
        ss[c] = sc;
        ss[OCH + c] = beta[c] - mean * sc;
    }
}

// ---------------- kernel 5: BN apply + PReLU ----------------
__global__ __launch_bounds__(256) void apply_bn(const float* __restrict__ ybuf,
                                                const float* __restrict__ ss,
                                                const float* __restrict__ prelu,
                                                float* __restrict__ out) {
    int i = blockIdx.x * 256 + threadIdx.x;       // float4 index, exact grid
    int oc = ((i * 4) >> 14) & 63;
    float sc = ss[oc], sh = ss[OCH + oc], pw = prelu[oc];
    float4 v = ((const float4*)ybuf)[i];
    float t;
    t = fmaf(v.x, sc, sh); v.x = t >= 0.f ? t : pw * t;
    t = fmaf(v.y, sc, sh); v.y = t >= 0.f ? t : pw * t;
    t = fmaf(v.z, sc, sh); v.z = t >= 0.f ? t : pw * t;
    t = fmaf(v.w, sc, sh); v.w = t >= 0.f ? t : pw * t;
    ((float4*)out)[i] = v;
}

extern "C" void kernel_launch(void* const* d_in, const int* in_sizes, int n_in,
                              void* d_out, int out_size, void* d_ws, size_t ws_size,
                              hipStream_t stream) {
    const float* x      = (const float*)d_in[0];
    const float* w_off  = (const float*)d_in[1];
    const float* b_off  = (const float*)d_in[2];
    const float* w_def  = (const float*)d_in[3];
    const float* b_def  = (const float*)d_in[4];
    const float* gamma  = (const float*)d_in[5];
    const float* beta   = (const float*)d_in[6];
    const float* prelu  = (const float*)d_in[7];

    float* ws    = (float*)d_ws;
    float* ybuf  = ws + Y_OFF;
    float* offs  = ws + OFFS_OFF;
    float* wof2  = ws + WOFF2_OFF;
    short* wtb   = (short*)(ws + WTB_OFF);
    float* stats = ws + STATS_OFF;
    float* gsum  = stats;
    float* gsq   = stats + OCH;
    float* ss    = stats + 2 * OCH;

    // xt (NHWC x) lives in d_out: dead by the time apply_bn rewrites it.
    float* xt = (float*)d_out;

    hipMemsetAsync(stats, 0, 2 * OCH * sizeof(float), stream);
    prep_w<<<185, 256, 0, stream>>>(w_def, w_off, wtb, wof2);
    transpose_x<<<BSZ * HWSZ / 32, 256, 0, stream>>>(x, xt);
    offset_conv<<<BSZ * HH * 2, 256, 0, stream>>>(xt, b_off, wof2, offs);
    deform_mfma<<<BSZ * HH * 2, 256, 0, stream>>>(xt, offs, wtb, b_def, ybuf, gsum, gsq);
    finalize_bn<<<1, 64, 0, stream>>>(gsum, gsq, gamma, beta, ss);
    apply_bn<<<(BSZ * OCH * HWSZ) / 4 / 256, 256, 0, stream>>>(ybuf, ss, prelu, (float*)d_out);
}

// Round 12
// 237.762 us; speedup vs baseline: 1.2640x; 1.2640x over previous
//
#include <hip/hip_runtime.h>

#define BSZ 4
#define CIN 64
#define HH 128
#define WW 128
#define OCH 64
#define HWSZ (HH*WW)
#define KK 9
#define NPIX (BSZ*HH*WW)

typedef __attribute__((ext_vector_type(8))) short short8v;
typedef __attribute__((ext_vector_type(8))) unsigned short ushort8v;
typedef __attribute__((ext_vector_type(4))) float float4v;

// ws layout (float slots)
#define Y_OFF     0                                 // ybuf bf16: 4.2M shorts = 2097152 float slots
#define OFFS_OFF  2097152                           // [b][ho][wo][20] = 1310720 floats
#define WOFF2_OFF (OFFS_OFF + BSZ*HWSZ*20)          // 3407872; 10368 floats
#define WTB_OFF   (WOFF2_OFF + 576*18)              // 3418240; 36864 bf16 = 18432 float slots
#define STATS_OFF (WTB_OFF + 18432)                 // 3436672; gsum[64] gsq[64] ss[128]

__device__ __forceinline__ short f2bf(float f) {
    unsigned u = __builtin_bit_cast(unsigned, f);
    unsigned r = (u + 0x7FFFu + ((u >> 16) & 1u)) >> 16;
    return (short)r;
}
__device__ __forceinline__ float bf2f(unsigned short u) {
    return __builtin_bit_cast(float, ((unsigned)u) << 16);
}

// ---------------- kernel 0: weight prep ----------------
__global__ void prep_w(const float* __restrict__ w_def,
                       const float* __restrict__ w_off,
                       short* __restrict__ wtb,      // [k][oc][c] bf16
                       float* __restrict__ wof2) {   // [tap][c][18]
    int i = blockIdx.x * 256 + threadIdx.x;
    if (i < 36864) {
        int oc = i / 576, rr = i % 576;
        int c = rr / 9, k = rr % 9;
        wtb[(k * OCH + oc) * CIN + c] = f2bf(w_def[i]);
    } else if (i < 36864 + 10368) {
        int j = i - 36864;
        int o = j / 576, rr = j % 576;
        int c = rr / 9, tap = rr % 9;
        wof2[(tap * CIN + c) * 18 + o] = w_off[j];
    }
}

// ---------------- kernel 1: x NCHW -> NHWC bf16 via LDS tile ----------------
// grid 2048 blocks, 32 px per block, XCD-swizzled.
__global__ __launch_bounds__(256, 8) void transpose_x(const float* __restrict__ x,
                                                      unsigned short* __restrict__ xt) {
    __shared__ float t[64][33];
    const int bid = blockIdx.x;
    const int wg  = (bid & 7) * 256 + (bid >> 3);   // 2048/8 = 256 per XCD
    const int tid = threadIdx.x;
    const int gp0 = wg * 32;                         // b*16384 + hw0
    const int b   = gp0 >> 14;
    const int hw0 = gp0 & 16383;
    const float* src = x + b * CIN * HWSZ + hw0;
    #pragma unroll
    for (int pass = 0; pass < 8; ++pass) {
        int c = pass * 8 + (tid >> 5);
        int p = tid & 31;
        t[c][p] = src[c * HWSZ + p];
    }
    __syncthreads();
    unsigned short* dst = xt + (b * HWSZ + hw0) * 64;
    #pragma unroll
    for (int pass = 0; pass < 8; ++pass) {
        int p = pass * 4 + (tid >> 6);
        int c = tid & 63;
        dst[p * 64 + c] = (unsigned short)f2bf(t[c][p]);
    }
}

// ---------------- kernel 2: 3x3 offset conv (bf16 NHWC reads) ----------------
__global__ __launch_bounds__(256, 4) void offset_conv(
    const unsigned short* __restrict__ xt,
    const float* __restrict__ b_off,
    const float* __restrict__ wof2,
    float* __restrict__ offs)   // [b][ho][wo][20]
{
    __shared__ float part[2][9][64];   // q2==1 partials
    const int bid = blockIdx.x;
    const int wg  = (bid & 7) * 128 + (bid >> 3);   // 1024/8 = 128 per XCD
    const int tid = threadIdx.x;
    const int lane = tid & 63;
    const int wvv = __builtin_amdgcn_readfirstlane(tid >> 6);
    const int og  = wvv & 1;
    const int q2  = wvv >> 1;
    const int row = wg >> 1, half = wg & 1;
    const int b = row >> 7, ho = row & 127;
    const int px = half * 64 + lane;

    float oacc[9];
    #pragma unroll
    for (int j = 0; j < 9; ++j) oacc[j] = (q2 == 0) ? b_off[og * 9 + j] : 0.f;

    const unsigned short* xb = xt + b * HWSZ * 64;
    #pragma unroll
    for (int tap = 0; tap < 9; ++tap) {
        const int kh = tap / 3, kw = tap % 3;
        const int yy = ho - 1 + kh;
        const int xx = px - 1 + kw;
        if (((unsigned)yy < (unsigned)HH) & ((unsigned)xx < (unsigned)WW)) {
            const unsigned short* pv = xb + (yy * WW + xx) * 64 + q2 * 32;
            const float* wp = wof2 + (tap * CIN + q2 * 32) * 18 + og * 9;
            #pragma unroll
            for (int c8 = 0; c8 < 4; ++c8) {
                ushort8v xv = *(const ushort8v*)(pv + c8 * 8);
                #pragma unroll
                for (int cc = 0; cc < 8; ++cc) {
                    const float* w = wp + (c8 * 8 + cc) * 18;
                    float xs = bf2f(xv[cc]);
                    #pragma unroll
                    for (int j = 0; j < 9; ++j) oacc[j] = fmaf(xs, w[j], oacc[j]);
                }
            }
        }
    }
    if (q2 == 1) {
        #pragma unroll
        for (int j = 0; j < 9; ++j) part[og][j][lane] = oacc[j];
    }
    __syncthreads();
    if (q2 == 0) {
        float* orow = offs + ((b * HH + ho) * WW + px) * 20 + og * 9;
        #pragma unroll
        for (int j = 0; j < 9; ++j) orow[j] = oacc[j] + part[og][j][lane];
    }
}

// ---------------- kernel 3: deform conv via MFMA (bf16 NHWC gathers) ----------------
__global__ __launch_bounds__(256, 4) void deform_mfma(
    const unsigned short* __restrict__ xt,  // NHWC bf16
    const float* __restrict__ offs,         // [b][ho][wo][20]
    const short* __restrict__ wtb,
    const float* __restrict__ b_def,
    unsigned short* __restrict__ ybuf,      // bf16
    float* __restrict__ gsum,
    float* __restrict__ gsq)
{
    __shared__ float red0[4][64];
    __shared__ float red1[4][64];

    const int bid  = blockIdx.x;
    const int r    = (bid & 7) * 128 + (bid >> 3);   // XCD swizzle
    const int tid  = threadIdx.x;
    const int lane = tid & 63;
    const int wv   = tid >> 6;
    const int b    = r >> 8;
    const int rem  = r & 255;
    const int ho   = rem >> 1, half = rem & 1;
    const int l15  = lane & 15;
    const int l4   = lane >> 4;
    const int cbase = l4 * 8;
    const int p    = half * 64 + wv * 16 + l15;   // this lane's pixel

    float4v acc[4];
    #pragma unroll
    for (int mt = 0; mt < 4; ++mt) acc[mt] = (float4v){0.f, 0.f, 0.f, 0.f};

    const unsigned short* xb = xt + b * HWSZ * 64;

    // hoist all 18 offsets for this pixel
    float och[18];
    {
        const float* op = offs + ((b * HH + ho) * WW + p) * 20;
        float4 o0 = *(const float4*)(op);
        float4 o1 = *(const float4*)(op + 4);
        float4 o2 = *(const float4*)(op + 8);
        float4 o3 = *(const float4*)(op + 12);
        float4 o4 = *(const float4*)(op + 16);
        och[0]=o0.x; och[1]=o0.y; och[2]=o0.z; och[3]=o0.w;
        och[4]=o1.x; och[5]=o1.y; och[6]=o1.z; och[7]=o1.w;
        och[8]=o2.x; och[9]=o2.y; och[10]=o2.z; och[11]=o2.w;
        och[12]=o3.x; och[13]=o3.y; och[14]=o3.z; och[15]=o3.w;
        och[16]=o4.x; och[17]=o4.y;
    }

    #pragma unroll
    for (int k = 0; k < KK; ++k) {
        float dy = och[2 * k];
        float dx = och[2 * k + 1];
        float py = (float)(ho - 1 + (k / 3)) + dy;
        float px = (float)(p - 1 + (k % 3)) + dx;
        float y0f = floorf(py), x0f = floorf(px);
        int y0 = (int)y0f, x0 = (int)x0f;
        float wy1 = py - y0f, wy0 = 1.f - wy1;
        float wx1 = px - x0f, wx0 = 1.f - wx1;
        int vy0 = ((unsigned)y0 < (unsigned)HH), vy1 = ((unsigned)(y0 + 1) < (unsigned)HH);
        int vx0 = ((unsigned)x0 < (unsigned)WW), vx1 = ((unsigned)(x0 + 1) < (unsigned)WW);
        float w00 = wy0 * wx0 * (float)(vy0 & vx0);
        float w01 = wy0 * wx1 * (float)(vy0 & vx1);
        float w10 = wy1 * wx0 * (float)(vy1 & vx0);
        float w11 = wy1 * wx1 * (float)(vy1 & vx1);
        int y0c = min(max(y0, 0), HH - 1), y1c = min(max(y0 + 1, 0), HH - 1);
        int x0c = min(max(x0, 0), WW - 1), x1c = min(max(x0 + 1, 0), WW - 1);
        const unsigned short* p00 = xb + (y0c * WW + x0c) * 64 + cbase;
        const unsigned short* p01 = xb + (y0c * WW + x1c) * 64 + cbase;
        const unsigned short* p10 = xb + (y1c * WW + x0c) * 64 + cbase;
        const unsigned short* p11 = xb + (y1c * WW + x1c) * 64 + cbase;

        // issue all 8 gathers for this tap before any math (MLP)
        ushort8v g00a = *(const ushort8v*)(p00);
        ushort8v g01a = *(const ushort8v*)(p01);
        ushort8v g10a = *(const ushort8v*)(p10);
        ushort8v g11a = *(const ushort8v*)(p11);
        ushort8v g00b = *(const ushort8v*)(p00 + 32);
        ushort8v g01b = *(const ushort8v*)(p01 + 32);
        ushort8v g10b = *(const ushort8v*)(p10 + 32);
        ushort8v g11b = *(const ushort8v*)(p11 + 32);

        short8v Bf[2];
        #pragma unroll
        for (int j = 0; j < 8; ++j) {
            float v = bf2f(g00a[j]) * w00 + bf2f(g01a[j]) * w01
                    + bf2f(g10a[j]) * w10 + bf2f(g11a[j]) * w11;
            Bf[0][j] = f2bf(v);
        }
        #pragma unroll
        for (int j = 0; j < 8; ++j) {
            float v = bf2f(g00b[j]) * w00 + bf2f(g01b[j]) * w01
                    + bf2f(g10b[j]) * w10 + bf2f(g11b[j]) * w11;
            Bf[1][j] = f2bf(v);
        }

        const short* wk = wtb + k * OCH * CIN;
        #pragma unroll
        for (int mt = 0; mt < 4; ++mt) {
            const short* wrow = wk + (mt * 16 + l15) * CIN + cbase;
            #pragma unroll
            for (int kc = 0; kc < 2; ++kc) {
                short8v Af = *(const short8v*)(wrow + kc * 32);
                acc[mt] = __builtin_amdgcn_mfma_f32_16x16x32_bf16(Af, Bf[kc], acc[mt], 0, 0, 0);
            }
        }
    }

    // ---- epilogue: bias, y store (bf16), BN partials ----
    // C/D layout: col(pix)=lane&15, row(oc)=(lane>>4)*4+reg
    float lsum[4][4], lsq[4][4];
    const int yrow = ho * WW;
    #pragma unroll
    for (int mt = 0; mt < 4; ++mt) {
        #pragma unroll
        for (int rr = 0; rr < 4; ++rr) {
            const int oc = mt * 16 + l4 * 4 + rr;
            float v = acc[mt][rr] + b_def[oc];
            ybuf[(b * OCH + oc) * HWSZ + yrow + p] = (unsigned short)f2bf(v);
            lsum[mt][rr] = v;
            lsq[mt][rr]  = v * v;
        }
    }
    #pragma unroll
    for (int m = 1; m <= 8; m <<= 1) {
        #pragma unroll
        for (int mt = 0; mt < 4; ++mt)
            #pragma unroll
            for (int rr = 0; rr < 4; ++rr) {
                lsum[mt][rr] += __shfl_xor(lsum[mt][rr], m);
                lsq[mt][rr]  += __shfl_xor(lsq[mt][rr], m);
            }
    }
    if (l15 == 0) {
        #pragma unroll
        for (int mt = 0; mt < 4; ++mt)
            #pragma unroll
            for (int rr = 0; rr < 4; ++rr) {
                const int oc = mt * 16 + l4 * 4 + rr;
                red0[wv][oc] = lsum[mt][rr];
                red1[wv][oc] = lsq[mt][rr];
            }
    }
    __syncthreads();
    if (tid < 128) {
        const int oc = tid & 63, s = tid >> 6;
        if (s == 0) {
            float v = red0[0][oc] + red0[1][oc] + red0[2][oc] + red0[3][oc];
            atomicAdd(&gsum[oc], v);
        } else {
            float v = red1[0][oc] + red1[1][oc] + red1[2][oc] + red1[3][oc];
            atomicAdd(&gsq[oc], v);
        }
    }
}

// ---------------- kernel 4: BN stats finalize ----------------
__global__ void finalize_bn(const float* __restrict__ gsum, const float* __restrict__ gsq,
                            const float* __restrict__ gamma, const float* __restrict__ beta,
                            float* __restrict__ ss) {
    int c = threadIdx.x;
    if (c < OCH) {
        const float inv = 1.f / (float)NPIX;
        float mean = gsum[c] * inv;
        float var = gsq[c] * inv - mean * mean;
        float rstd = rsqrtf(var + 1e-5f);
        float sc = gamma[c] * rstd;
        ss[c] = sc;
        ss[OCH + c] = beta[c] - mean * sc;
    }
}

// ---------------- kernel 5: BN apply + PReLU (bf16 y -> f32 out) ----------------
__global__ __launch_bounds__(256) void apply_bn(const unsigned short* __restrict__ ybuf,
                                                const float* __restrict__ ss,
                                                const float* __restrict__ prelu,
                                                float* __restrict__ out) {
    int i = blockIdx.x * 256 + threadIdx.x;       // ushort8 group index, exact grid
    int oc = ((i * 8) >> 14) & 63;
    float sc = ss[oc], sh = ss[OCH + oc], pw = prelu[oc];
    ushort8v v8 = ((const ushort8v*)ybuf)[i];
    float4 o0, o1;
    float t;
    t = fmaf(bf2f(v8[0]), sc, sh); o0.x = t >= 0.f ? t : pw * t;
    t = fmaf(bf2f(v8[1]), sc, sh); o0.y = t >= 0.f ? t : pw * t;
    t = fmaf(bf2f(v8[2]), sc, sh); o0.z = t >= 0.f ? t : pw * t;
    t = fmaf(bf2f(v8[3]), sc, sh); o0.w = t >= 0.f ? t : pw * t;
    t = fmaf(bf2f(v8[4]), sc, sh); o1.x = t >= 0.f ? t : pw * t;
    t = fmaf(bf2f(v8[5]), sc, sh); o1.y = t >= 0.f ? t : pw * t;
    t = fmaf(bf2f(v8[6]), sc, sh); o1.z = t >= 0.f ? t : pw * t;
    t = fmaf(bf2f(v8[7]), sc, sh); o1.w = t >= 0.f ? t : pw * t;
    ((float4*)out)[i * 2]     = o0;
    ((float4*)out)[i * 2 + 1] = o1;
}

extern "C" void kernel_launch(void* const* d_in, const int* in_sizes, int n_in,
                              void* d_out, int out_size, void* d_ws, size_t ws_size,
                              hipStream_t stream) {
    const float* x      = (const float*)d_in[0];
    const float* w_off  = (const float*)d_in[1];
    const float* b_off  = (const float*)d_in[2];
    const float* w_def  = (const float*)d_in[3];
    const float* b_def  = (const float*)d_in[4];
    const float* gamma  = (const float*)d_in[5];
    const float* beta   = (const float*)d_in[6];
    const float* prelu  = (const float*)d_in[7];

    float* ws    = (float*)d_ws;
    unsigned short* ybuf = (unsigned short*)(ws + Y_OFF);
    float* offs  = ws + OFFS_OFF;
    float* wof2  = ws + WOFF2_OFF;
    short* wtb   = (short*)(ws + WTB_OFF);
    float* stats = ws + STATS_OFF;
    float* gsum  = stats;
    float* gsq   = stats + OCH;
    float* ss    = stats + 2 * OCH;

    // xt (NHWC bf16 x) lives in d_out: dead by the time apply_bn rewrites it.
    unsigned short* xt = (unsigned short*)d_out;

    hipMemsetAsync(stats, 0, 2 * OCH * sizeof(float), stream);
    prep_w<<<185, 256, 0, stream>>>(w_def, w_off, wtb, wof2);
    transpose_x<<<BSZ * HWSZ / 32, 256, 0, stream>>>(x, xt);
    offset_conv<<<BSZ * HH * 2, 256, 0, stream>>>(xt, b_off, wof2, offs);
    deform_mfma<<<BSZ * HH * 2, 256, 0, stream>>>(xt, offs, wtb, b_def, ybuf, gsum, gsq);
    finalize_bn<<<1, 64, 0, stream>>>(gsum, gsq, gamma, beta, ss);
    apply_bn<<<(BSZ * OCH * HWSZ) / 8 / 256, 256, 0, stream>>>(ybuf, ss, prelu, (float*)d_out);
}

// Round 14
// 190.837 us; speedup vs baseline: 1.5748x; 1.2459x over previous
//
#include <hip/hip_runtime.h>

#define BSZ 4
#define CIN 64
#define HH 128
#define WW 128
#define OCH 64
#define HWSZ (HH*WW)
#define KK 9
#define NPIX (BSZ*HH*WW)

typedef __attribute__((ext_vector_type(8))) short short8v;
typedef __attribute__((ext_vector_type(8))) unsigned short ushort8v;
typedef __attribute__((ext_vector_type(4))) float float4v;

// ws layout (float slots)
#define Y_OFF     0                                 // ybuf bf16: 4.2M shorts = 2097152 float slots
#define WTB_OFF   2097152                           // 36864 bf16 = 18432 float slots
#define WOFB_OFF  (WTB_OFF + 18432)                 // 32*576 bf16 = 18432 shorts = 9216 float slots
#define STATS_OFF (WOFB_OFF + 9216)                 // gsum[64] gsq[64] ss[128]

__device__ __forceinline__ short f2bf(float f) {
    unsigned u = __builtin_bit_cast(unsigned, f);
    unsigned r = (u + 0x7FFFu + ((u >> 16) & 1u)) >> 16;
    return (short)r;
}
__device__ __forceinline__ float bf2f(unsigned short u) {
    return __builtin_bit_cast(float, ((unsigned)u) << 16);
}

// ---------------- kernel 0: weight prep ----------------
// wtb: [k][oc][c] bf16 ; wofb: [32(pad)][tap][c] bf16 (rows 18..31 zero)
__global__ void prep_w(const float* __restrict__ w_def,
                       const float* __restrict__ w_off,
                       short* __restrict__ wtb,
                       short* __restrict__ wofb) {
    int i = blockIdx.x * 256 + threadIdx.x;
    if (i < 36864) {
        int oc = i / 576, rr = i % 576;
        int c = rr / 9, k = rr % 9;
        wtb[(k * OCH + oc) * CIN + c] = f2bf(w_def[i]);
    } else if (i < 36864 + 18432) {
        int j = i - 36864;
        int o = j / 576, rr = j % 576;
        int tap = rr / 64, c = rr % 64;
        wofb[j] = (o < 18) ? f2bf(w_off[(o * 64 + c) * 9 + tap]) : (short)0;
    }
}

// ---------------- kernel 1: x NCHW -> NHWC bf16 via LDS tile ----------------
__global__ __launch_bounds__(256, 8) void transpose_x(const float* __restrict__ x,
                                                      unsigned short* __restrict__ xt) {
    __shared__ float t[64][33];
    const int bid = blockIdx.x;
    const int wg  = (bid & 7) * 256 + (bid >> 3);   // 2048/8 = 256 per XCD
    const int tid = threadIdx.x;
    const int gp0 = wg * 32;
    const int b   = gp0 >> 14;
    const int hw0 = gp0 & 16383;
    const float* src = x + b * CIN * HWSZ + hw0;
    #pragma unroll
    for (int pass = 0; pass < 8; ++pass) {
        int c = pass * 8 + (tid >> 5);
        int p = tid & 31;
        t[c][p] = src[c * HWSZ + p];
    }
    __syncthreads();
    unsigned short* dst = xt + (b * HWSZ + hw0) * 64;
    #pragma unroll
    for (int pass = 0; pass < 8; ++pass) {
        int p = pass * 4 + (tid >> 6);
        int c = tid & 63;
        dst[p * 64 + c] = (unsigned short)f2bf(t[c][p]);
    }
}

// ---------------- kernel 2: fused offset-conv(MFMA) + deform conv(MFMA) ----------------
__global__ __launch_bounds__(256, 4) void deform_fused(
    const unsigned short* __restrict__ xt,  // NHWC bf16
    const short* __restrict__ wofb,         // [32][tap][c] bf16
    const float* __restrict__ b_off,
    const short* __restrict__ wtb,          // [k][oc][c] bf16
    const float* __restrict__ b_def,
    unsigned short* __restrict__ ybuf,      // bf16
    float* __restrict__ gsum,
    float* __restrict__ gsq)
{
    __shared__ float off_lds[18][64];
    __shared__ float red0[4][64];
    __shared__ float red1[4][64];

    const int bid  = blockIdx.x;
    const int r    = (bid & 7) * 128 + (bid >> 3);   // XCD swizzle
    const int tid  = threadIdx.x;
    const int lane = tid & 63;
    const int wv   = tid >> 6;
    const int b    = r >> 8;
    const int rem  = r & 255;
    const int ho   = rem >> 1, half = rem & 1;
    const int l15  = lane & 15;
    const int l4   = lane >> 4;
    const int cbase = l4 * 8;
    const int p    = half * 64 + wv * 16 + l15;   // this lane's pixel

    const unsigned short* xb = xt + b * HWSZ * 64;

    // ---- phase A: offset conv via MFMA (18 out-ch, K=576 tap-major) ----
    {
        float4v offacc0 = (float4v){0.f, 0.f, 0.f, 0.f};
        float4v offacc1 = (float4v){0.f, 0.f, 0.f, 0.f};
        const ushort8v zero8 = {0, 0, 0, 0, 0, 0, 0, 0};
        #pragma unroll
        for (int kk = 0; kk < 18; ++kk) {
            const int tap = kk >> 1;
            const int kh = tap / 3, kw = tap % 3;
            const int yy = ho - 1 + kh;
            const int xx = p - 1 + kw;
            const bool valid = ((unsigned)yy < (unsigned)HH) & ((unsigned)xx < (unsigned)WW);
            const int pix = valid ? (yy * WW + xx) : 0;
            ushort8v bo = *(const ushort8v*)(xb + pix * 64 + (kk & 1) * 32 + cbase);
            if (!valid) bo = zero8;
            short8v bos = __builtin_bit_cast(short8v, bo);
            short8v af0 = *(const short8v*)(wofb + (l15) * 576 + kk * 32 + cbase);
            short8v af1 = *(const short8v*)(wofb + (16 + l15) * 576 + kk * 32 + cbase);
            offacc0 = __builtin_amdgcn_mfma_f32_16x16x32_bf16(af0, bos, offacc0, 0, 0, 0);
            offacc1 = __builtin_amdgcn_mfma_f32_16x16x32_bf16(af1, bos, offacc1, 0, 0, 0);
        }
        // D layout: col=l15, row=l4*4+rr. Redistribute rows->pixels via LDS.
        const int col = wv * 16 + l15;
        #pragma unroll
        for (int rr = 0; rr < 4; ++rr) {
            int row = l4 * 4 + rr;
            off_lds[row][col] = offacc0[rr] + b_off[row];   // rows 0..15
        }
        if (l4 == 0) {
            #pragma unroll
            for (int rr = 0; rr < 2; ++rr) {
                int row = 16 + rr;
                off_lds[row][col] = offacc1[rr] + b_off[row];
            }
        }
    }
    __syncthreads();

    float och[18];
    {
        const int col = wv * 16 + l15;
        #pragma unroll
        for (int j = 0; j < 18; ++j) och[j] = off_lds[j][col];
    }

    // ---- phase B: deform conv via MFMA (bf16 NHWC gathers) ----
    float4v acc[4];
    #pragma unroll
    for (int mt = 0; mt < 4; ++mt) acc[mt] = (float4v){0.f, 0.f, 0.f, 0.f};

    #pragma unroll
    for (int k = 0; k < KK; ++k) {
        float dy = och[2 * k];
        float dx = och[2 * k + 1];
        float py = (float)(ho - 1 + (k / 3)) + dy;
        float px = (float)(p - 1 + (k % 3)) + dx;
        float y0f = floorf(py), x0f = floorf(px);
        int y0 = (int)y0f, x0 = (int)x0f;
        float wy1 = py - y0f, wy0 = 1.f - wy1;
        float wx1 = px - x0f, wx0 = 1.f - wx1;
        int vy0 = ((unsigned)y0 < (unsigned)HH), vy1 = ((unsigned)(y0 + 1) < (unsigned)HH);
        int vx0 = ((unsigned)x0 < (unsigned)WW), vx1 = ((unsigned)(x0 + 1) < (unsigned)WW);
        float w00 = wy0 * wx0 * (float)(vy0 & vx0);
        float w01 = wy0 * wx1 * (float)(vy0 & vx1);
        float w10 = wy1 * wx0 * (float)(vy1 & vx0);
        float w11 = wy1 * wx1 * (float)(vy1 & vx1);
        int y0c = min(max(y0, 0), HH - 1), y1c = min(max(y0 + 1, 0), HH - 1);
        int x0c = min(max(x0, 0), WW - 1), x1c = min(max(x0 + 1, 0), WW - 1);
        const unsigned short* p00 = xb + (y0c * WW + x0c) * 64 + cbase;
        const unsigned short* p01 = xb + (y0c * WW + x1c) * 64 + cbase;
        const unsigned short* p10 = xb + (y1c * WW + x0c) * 64 + cbase;
        const unsigned short* p11 = xb + (y1c * WW + x1c) * 64 + cbase;

        ushort8v g00a = *(const ushort8v*)(p00);
        ushort8v g01a = *(const ushort8v*)(p01);
        ushort8v g10a = *(const ushort8v*)(p10);
        ushort8v g11a = *(const ushort8v*)(p11);
        ushort8v g00b = *(const ushort8v*)(p00 + 32);
        ushort8v g01b = *(const ushort8v*)(p01 + 32);
        ushort8v g10b = *(const ushort8v*)(p10 + 32);
        ushort8v g11b = *(const ushort8v*)(p11 + 32);

        short8v Bf[2];
        #pragma unroll
        for (int j = 0; j < 8; ++j) {
            float v = bf2f(g00a[j]) * w00 + bf2f(g01a[j]) * w01
                    + bf2f(g10a[j]) * w10 + bf2f(g11a[j]) * w11;
            Bf[0][j] = f2bf(v);
        }
        #pragma unroll
        for (int j = 0; j < 8; ++j) {
            float v = bf2f(g00b[j]) * w00 + bf2f(g01b[j]) * w01
                    + bf2f(g10b[j]) * w10 + bf2f(g11b[j]) * w11;
            Bf[1][j] = f2bf(v);
        }

        const short* wk = wtb + k * OCH * CIN;
        #pragma unroll
        for (int mt = 0; mt < 4; ++mt) {
            const short* wrow = wk + (mt * 16 + l15) * CIN + cbase;
            #pragma unroll
            for (int kc = 0; kc < 2; ++kc) {
                short8v Af = *(const short8v*)(wrow + kc * 32);
                acc[mt] = __builtin_amdgcn_mfma_f32_16x16x32_bf16(Af, Bf[kc], acc[mt], 0, 0, 0);
            }
        }
    }

    // ---- epilogue: bias, y store (bf16), BN partials ----
    float lsum[4][4], lsq[4][4];
    const int yrow = ho * WW;
    #pragma unroll
    for (int mt = 0; mt < 4; ++mt) {
        #pragma unroll
        for (int rr = 0; rr < 4; ++rr) {
            const int oc = mt * 16 + l4 * 4 + rr;
            float v = acc[mt][rr] + b_def[oc];
            ybuf[(b * OCH + oc) * HWSZ + yrow + p] = (unsigned short)f2bf(v);
            lsum[mt][rr] = v;
            lsq[mt][rr]  = v * v;
        }
    }
    #pragma unroll
    for (int m = 1; m <= 8; m <<= 1) {
        #pragma unroll
        for (int mt = 0; mt < 4; ++mt)
            #pragma unroll
            for (int rr = 0; rr < 4; ++rr) {
                lsum[mt][rr] += __shfl_xor(lsum[mt][rr], m);
                lsq[mt][rr]  += __shfl_xor(lsq[mt][rr], m);
            }
    }
    if (l15 == 0) {
        #pragma unroll
        for (int mt = 0; mt < 4; ++mt)
            #pragma unroll
            for (int rr = 0; rr < 4; ++rr) {
                const int oc = mt * 16 + l4 * 4 + rr;
                red0[wv][oc] = lsum[mt][rr];
                red1[wv][oc] = lsq[mt][rr];
            }
    }
    __syncthreads();
    if (tid < 128) {
        const int oc = tid & 63, s = tid >> 6;
        if (s == 0) {
            float v = red0[0][oc] + red0[1][oc] + red0[2][oc] + red0[3][oc];
            atomicAdd(&gsum[oc], v);
        } else {
            float v = red1[0][oc] + red1[1][oc] + red1[2][oc] + red1[3][oc];
            atomicAdd(&gsq[oc], v);
        }
    }
}

// ---------------- kernel 3: BN stats finalize ----------------
__global__ void finalize_bn(const float* __restrict__ gsum, const float* __restrict__ gsq,
                            const float* __restrict__ gamma, const float* __restrict__ beta,
                            float* __restrict__ ss) {
    int c = threadIdx.x;
    if (c < OCH) {
        const float inv = 1.f / (float)NPIX;
        float mean = gsum[c] * inv;
        float var = gsq[c] * inv - mean * mean;
        float rstd = rsqrtf(var + 1e-5f);
        float sc = gamma[c] * rstd;
        ss[c] = sc;
        ss[OCH + c] = beta[c] - mean * sc;
    }
}

// ---------------- kernel 4: BN apply + PReLU (bf16 y -> f32 out) ----------------
__global__ __launch_bounds__(256) void apply_bn(const unsigned short* __restrict__ ybuf,
                                                const float* __restrict__ ss,
                                                const float* __restrict__ prelu,
                                                float* __restrict__ out) {
    int i = blockIdx.x * 256 + threadIdx.x;       // ushort8 group index, exact grid
    int oc = ((i * 8) >> 14) & 63;
    float sc = ss[oc], sh = ss[OCH + oc], pw = prelu[oc];
    ushort8v v8 = ((const ushort8v*)ybuf)[i];
    float4 o0, o1;
    float t;
    t = fmaf(bf2f(v8[0]), sc, sh); o0.x = t >= 0.f ? t : pw * t;
    t = fmaf(bf2f(v8[1]), sc, sh); o0.y = t >= 0.f ? t : pw * t;
    t = fmaf(bf2f(v8[2]), sc, sh); o0.z = t >= 0.f ? t : pw * t;
    t = fmaf(bf2f(v8[3]), sc, sh); o0.w = t >= 0.f ? t : pw * t;
    t = fmaf(bf2f(v8[4]), sc, sh); o1.x = t >= 0.f ? t : pw * t;
    t = fmaf(bf2f(v8[5]), sc, sh); o1.y = t >= 0.f ? t : pw * t;
    t = fmaf(bf2f(v8[6]), sc, sh); o1.z = t >= 0.f ? t : pw * t;
    t = fmaf(bf2f(v8[7]), sc, sh); o1.w = t >= 0.f ? t : pw * t;
    ((float4*)out)[i * 2]     = o0;
    ((float4*)out)[i * 2 + 1] = o1;
}

extern "C" void kernel_launch(void* const* d_in, const int* in_sizes, int n_in,
                              void* d_out, int out_size, void* d_ws, size_t ws_size,
                              hipStream_t stream) {
    const float* x      = (const float*)d_in[0];
    const float* w_off  = (const float*)d_in[1];
    const float* b_off  = (const float*)d_in[2];
    const float* w_def  = (const float*)d_in[3];
    const float* b_def  = (const float*)d_in[4];
    const float* gamma  = (const float*)d_in[5];
    const float* beta   = (const float*)d_in[6];
    const float* prelu  = (const float*)d_in[7];

    float* ws    = (float*)d_ws;
    unsigned short* ybuf = (unsigned short*)(ws + Y_OFF);
    short* wtb   = (short*)(ws + WTB_OFF);
    short* wofb  = (short*)(ws + WOFB_OFF);
    float* stats = ws + STATS_OFF;
    float* gsum  = stats;
    float* gsq   = stats + OCH;
    float* ss    = stats + 2 * OCH;

    // xt (NHWC bf16 x) lives in d_out: dead by the time apply_bn rewrites it.
    unsigned short* xt = (unsigned short*)d_out;

    hipMemsetAsync(stats, 0, 2 * OCH * sizeof(float), stream);
    prep_w<<<216, 256, 0, stream>>>(w_def, w_off, wtb, wofb);
    transpose_x<<<BSZ * HWSZ / 32, 256, 0, stream>>>(x, xt);
    deform_fused<<<BSZ * HH * 2, 256, 0, stream>>>(xt, wofb, b_off, wtb, b_def, ybuf, gsum, gsq);
    finalize_bn<<<1, 64, 0, stream>>>(gsum, gsq, gamma, beta, ss);
    apply_bn<<<(BSZ * OCH * HWSZ) / 8 / 256, 256, 0, stream>>>(ybuf, ss, prelu, (float*)d_out);
}

// Round 16
// 173.909 us; speedup vs baseline: 1.7281x; 1.0973x over previous
//
#include <hip/hip_runtime.h>

#define BSZ 4
#define CIN 64
#define HH 128
#define WW 128
#define OCH 64
#define HWSZ (HH*WW)
#define KK 9
#define NPIX (BSZ*HH*WW)

typedef __attribute__((ext_vector_type(8))) short short8v;
typedef __attribute__((ext_vector_type(8))) unsigned short ushort8v;
typedef __attribute__((ext_vector_type(4))) float float4v;

// ws layout (float slots)
#define Y_OFF     0                                 // ybuf bf16: 2097152 float slots
#define WTB_OFF   2097152                           // 36864 bf16 = 18432 float slots
#define WOFB_OFF  (WTB_OFF + 18432)                 // 32*576 bf16 = 9216 float slots
#define STATS_OFF (WOFB_OFF + 9216)                 // gsum[64] gsq[64] ss[128]

__device__ __forceinline__ short f2bf(float f) {
    unsigned u = __builtin_bit_cast(unsigned, f);
    unsigned r = (u + 0x7FFFu + ((u >> 16) & 1u)) >> 16;
    return (short)r;
}
__device__ __forceinline__ float bf2f(unsigned short u) {
    return __builtin_bit_cast(float, ((unsigned)u) << 16);
}

// ---------------- kernel 0: weight prep (+ stats zero) ----------------
__global__ void prep_w(const float* __restrict__ w_def,
                       const float* __restrict__ w_off,
                       short* __restrict__ wtb,
                       short* __restrict__ wofb,
                       float* __restrict__ stats) {
    int i = blockIdx.x * 256 + threadIdx.x;
    if (blockIdx.x == 0 && threadIdx.x < 128) stats[threadIdx.x] = 0.f;
    if (i < 36864) {
        int oc = i / 576, rr = i % 576;
        int c = rr / 9, k = rr % 9;
        wtb[(k * OCH + oc) * CIN + c] = f2bf(w_def[i]);
    } else if (i < 36864 + 18432) {
        int j = i - 36864;
        int o = j / 576, rr = j % 576;
        int tap = rr / 64, c = rr % 64;
        wofb[j] = (o < 18) ? f2bf(w_off[(o * 64 + c) * 9 + tap]) : (short)0;
    }
}

// ---------------- kernel 1: x NCHW -> NHWC bf16 via LDS tile ----------------
__global__ __launch_bounds__(256, 8) void transpose_x(const float* __restrict__ x,
                                                      unsigned short* __restrict__ xt) {
    __shared__ float t[64][33];
    const int bid = blockIdx.x;
    const int wg  = (bid & 7) * 256 + (bid >> 3);
    const int tid = threadIdx.x;
    const int gp0 = wg * 32;
    const int b   = gp0 >> 14;
    const int hw0 = gp0 & 16383;
    const float* src = x + b * CIN * HWSZ + hw0;
    #pragma unroll
    for (int pass = 0; pass < 8; ++pass) {
        int c = pass * 8 + (tid >> 5);
        int p = tid & 31;
        t[c][p] = src[c * HWSZ + p];
    }
    __syncthreads();
    unsigned short* dst = xt + (b * HWSZ + hw0) * 64;
    #pragma unroll
    for (int pass = 0; pass < 8; ++pass) {
        int p = pass * 4 + (tid >> 6);
        int c = tid & 63;
        dst[p * 64 + c] = (unsigned short)f2bf(t[c][p]);
    }
}

// ---------------- kernel 2: fused offset(MFMA) + deform(MFMA), LDS band ----------------
__global__ __launch_bounds__(256, 2) void deform_fused(
    const unsigned short* __restrict__ xt,  // NHWC bf16
    const short* __restrict__ wofb,         // [32][tap][c] bf16
    const float* __restrict__ b_off,
    const short* __restrict__ wtb,          // [k][oc][c] bf16
    const float* __restrict__ b_def,
    unsigned short* __restrict__ ybuf,      // bf16
    float* __restrict__ gsum,
    float* __restrict__ gsq)
{
    __shared__ unsigned short band[6 * 80 * 64];   // 60 KB, granule-XOR swizzled
    __shared__ float off_lds[18][64];
    __shared__ float red0[4][64];
    __shared__ float red1[4][64];

    const int bid  = blockIdx.x;
    const int r    = (bid & 7) * 128 + (bid >> 3);   // XCD swizzle
    const int tid  = threadIdx.x;
    const int lane = tid & 63;
    const int wv   = tid >> 6;
    const int b    = r >> 8;
    const int rem  = r & 255;
    const int ho   = rem >> 1, half = rem & 1;
    const int l15  = lane & 15;
    const int l4   = lane >> 4;
    const int cbase = l4 * 8;
    const int p    = half * 64 + wv * 16 + l15;   // this lane's pixel
    const int wx0  = half * 64 - 8;               // band col origin

    const unsigned short* xb = xt + b * HWSZ * 64;
    char* bandc = (char*)band;

    // ---- stage band: rows ho-2..ho+3, cols wx0..wx0+79 (swizzled) ----
    #pragma unroll
    for (int i = 0; i < 15; ++i) {
        int G  = i * 256 + tid;          // granule id, 3840 total
        int g  = G & 7;
        int xs = (G >> 3) % 80;
        int rs = G / 640;
        int row = min(max(ho - 2 + rs, 0), HH - 1);
        int col = min(max(wx0 + xs, 0), WW - 1);
        ushort8v v = *(const ushort8v*)(xb + (row * WW + col) * 64 + g * 8);
        int dstB = ((rs * 80 + xs) << 7) + ((g ^ (xs & 7)) << 4);
        *(ushort8v*)(bandc + dstB) = v;
    }
    __syncthreads();

    // ---- phase A: offset conv via MFMA (reads band) ----
    {
        float4v offacc0 = (float4v){0.f, 0.f, 0.f, 0.f};
        float4v offacc1 = (float4v){0.f, 0.f, 0.f, 0.f};
        const ushort8v zero8 = {0, 0, 0, 0, 0, 0, 0, 0};
        #pragma unroll
        for (int kk = 0; kk < 18; ++kk) {
            const int tap = kk >> 1;
            const int kh = tap / 3, kw = tap % 3;
            const int yy = ho - 1 + kh;
            const int xx = p - 1 + kw;
            const bool valid = ((unsigned)yy < (unsigned)HH) & ((unsigned)xx < (unsigned)WW);
            ushort8v bo = zero8;
            if (valid) {
                int xs = xx - wx0;                     // in [7,72]
                int q  = l4 + (kk & 1) * 4;
                int adr = (((kh + 1) * 80 + xs) << 7) + ((q ^ (xs & 7)) << 4);
                bo = *(const ushort8v*)(bandc + adr);
            }
            short8v bos = __builtin_bit_cast(short8v, bo);
            short8v af0 = *(const short8v*)(wofb + (l15) * 576 + kk * 32 + cbase);
            short8v af1 = *(const short8v*)(wofb + (16 + l15) * 576 + kk * 32 + cbase);
            offacc0 = __builtin_amdgcn_mfma_f32_16x16x32_bf16(af0, bos, offacc0, 0, 0, 0);
            offacc1 = __builtin_amdgcn_mfma_f32_16x16x32_bf16(af1, bos, offacc1, 0, 0, 0);
        }
        const int col = wv * 16 + l15;
        #pragma unroll
        for (int rr = 0; rr < 4; ++rr) {
            int row = l4 * 4 + rr;
            off_lds[row][col] = offacc0[rr] + b_off[row];
        }
        if (l4 == 0) {
            #pragma unroll
            for (int rr = 0; rr < 2; ++rr) {
                int row = 16 + rr;
                off_lds[row][col] = offacc1[rr] + b_off[row];
            }
        }
    }
    __syncthreads();

    float och[18];
    {
        const int col = wv * 16 + l15;
        #pragma unroll
        for (int j = 0; j < 18; ++j) och[j] = off_lds[j][col];
    }

    // ---- phase B: deform conv via MFMA (band gathers, global fallback) ----
    float4v acc[4];
    #pragma unroll
    for (int mt = 0; mt < 4; ++mt) acc[mt] = (float4v){0.f, 0.f, 0.f, 0.f};

    #pragma unroll
    for (int k = 0; k < KK; ++k) {
        float dy = och[2 * k];
        float dx = och[2 * k + 1];
        float py = (float)(ho - 1 + (k / 3)) + dy;
        float px = (float)(p - 1 + (k % 3)) + dx;
        float y0f = floorf(py), x0f = floorf(px);
        int y0 = (int)y0f, x0 = (int)x0f;
        float wy1 = py - y0f, wy0 = 1.f - wy1;
        float wx1 = px - x0f, wx0f_ = 1.f - wx1;
        int vy0 = ((unsigned)y0 < (unsigned)HH), vy1 = ((unsigned)(y0 + 1) < (unsigned)HH);
        int vx0 = ((unsigned)x0 < (unsigned)WW), vx1 = ((unsigned)(x0 + 1) < (unsigned)WW);
        float w00 = wy0 * wx0f_ * (float)(vy0 & vx0);
        float w01 = wy0 * wx1  * (float)(vy0 & vx1);
        float w10 = wy1 * wx0f_ * (float)(vy1 & vx0);
        float w11 = wy1 * wx1  * (float)(vy1 & vx1);
        int y0c = min(max(y0, 0), HH - 1), y1c = min(max(y0 + 1, 0), HH - 1);
        int x0c = min(max(x0, 0), WW - 1), x1c = min(max(x0 + 1, 0), WW - 1);

        int sy0 = y0c - (ho - 2), sy1 = y1c - (ho - 2);
        int sx0 = x0c - wx0,      sx1 = x1c - wx0;
        bool inb = (sy0 >= 0) & (sy1 < 6) & (sx0 >= 0) & (sx1 < 80);

        ushort8v g00a, g01a, g10a, g11a, g00b, g01b, g10b, g11b;
        if (__builtin_expect(inb, 1)) {
            const int qa = l4, qb = l4 + 4;
            int a00 = ((sy0 * 80 + sx0) << 7);
            int a01 = ((sy0 * 80 + sx1) << 7);
            int a10 = ((sy1 * 80 + sx0) << 7);
            int a11 = ((sy1 * 80 + sx1) << 7);
            int h0 = (sx0 & 7), h1 = (sx1 & 7);
            g00a = *(const ushort8v*)(bandc + a00 + ((qa ^ h0) << 4));
            g01a = *(const ushort8v*)(bandc + a01 + ((qa ^ h1) << 4));
            g10a = *(const ushort8v*)(bandc + a10 + ((qa ^ h0) << 4));
            g11a = *(const ushort8v*)(bandc + a11 + ((qa ^ h1) << 4));
            g00b = *(const ushort8v*)(bandc + a00 + ((qb ^ h0) << 4));
            g01b = *(const ushort8v*)(bandc + a01 + ((qb ^ h1) << 4));
            g10b = *(const ushort8v*)(bandc + a10 + ((qb ^ h0) << 4));
            g11b = *(const ushort8v*)(bandc + a11 + ((qb ^ h1) << 4));
        } else {
            const unsigned short* p00 = xb + (y0c * WW + x0c) * 64 + cbase;
            const unsigned short* p01 = xb + (y0c * WW + x1c) * 64 + cbase;
            const unsigned short* p10 = xb + (y1c * WW + x0c) * 64 + cbase;
            const unsigned short* p11 = xb + (y1c * WW + x1c) * 64 + cbase;
            g00a = *(const ushort8v*)(p00);      g01a = *(const ushort8v*)(p01);
            g10a = *(const ushort8v*)(p10);      g11a = *(const ushort8v*)(p11);
            g00b = *(const ushort8v*)(p00 + 32); g01b = *(const ushort8v*)(p01 + 32);
            g10b = *(const ushort8v*)(p10 + 32); g11b = *(const ushort8v*)(p11 + 32);
        }

        short8v Bf[2];
        #pragma unroll
        for (int j = 0; j < 8; ++j) {
            float v = bf2f(g00a[j]) * w00 + bf2f(g01a[j]) * w01
                    + bf2f(g10a[j]) * w10 + bf2f(g11a[j]) * w11;
            Bf[0][j] = f2bf(v);
        }
        #pragma unroll
        for (int j = 0; j < 8; ++j) {
            float v = bf2f(g00b[j]) * w00 + bf2f(g01b[j]) * w01
                    + bf2f(g10b[j]) * w10 + bf2f(g11b[j]) * w11;
            Bf[1][j] = f2bf(v);
        }

        const short* wk = wtb + k * OCH * CIN;
        #pragma unroll
        for (int mt = 0; mt < 4; ++mt) {
            const short* wrow = wk + (mt * 16 + l15) * CIN + cbase;
            #pragma unroll
            for (int kc = 0; kc < 2; ++kc) {
                short8v Af = *(const short8v*)(wrow + kc * 32);
                acc[mt] = __builtin_amdgcn_mfma_f32_16x16x32_bf16(Af, Bf[kc], acc[mt], 0, 0, 0);
            }
        }
    }

    // ---- epilogue: bias, y store (bf16), BN partials ----
    float lsum[4][4], lsq[4][4];
    const int yrow = ho * WW;
    #pragma unroll
    for (int mt = 0; mt < 4; ++mt) {
        #pragma unroll
        for (int rr = 0; rr < 4; ++rr) {
            const int oc = mt * 16 + l4 * 4 + rr;
            float v = acc[mt][rr] + b_def[oc];
            ybuf[(b * OCH + oc) * HWSZ + yrow + p] = (unsigned short)f2bf(v);
            lsum[mt][rr] = v;
            lsq[mt][rr]  = v * v;
        }
    }
    #pragma unroll
    for (int m = 1; m <= 8; m <<= 1) {
        #pragma unroll
        for (int mt = 0; mt < 4; ++mt)
            #pragma unroll
            for (int rr = 0; rr < 4; ++rr) {
                lsum[mt][rr] += __shfl_xor(lsum[mt][rr], m);
                lsq[mt][rr]  += __shfl_xor(lsq[mt][rr], m);
            }
    }
    if (l15 == 0) {
        #pragma unroll
        for (int mt = 0; mt < 4; ++mt)
            #pragma unroll
            for (int rr = 0; rr < 4; ++rr) {
                const int oc = mt * 16 + l4 * 4 + rr;
                red0[wv][oc] = lsum[mt][rr];
                red1[wv][oc] = lsq[mt][rr];
            }
    }
    __syncthreads();
    if (tid < 128) {
        const int oc = tid & 63, s = tid >> 6;
        if (s == 0) {
            float v = red0[0][oc] + red0[1][oc] + red0[2][oc] + red0[3][oc];
            atomicAdd(&gsum[oc], v);
        } else {
            float v = red1[0][oc] + red1[1][oc] + red1[2][oc] + red1[3][oc];
            atomicAdd(&gsq[oc], v);
        }
    }
}

// ---------------- kernel 3: BN stats finalize ----------------
__global__ void finalize_bn(const float* __restrict__ gsum, const float* __restrict__ gsq,
                            const float* __restrict__ gamma, const float* __restrict__ beta,
                            float* __restrict__ ss) {
    int c = threadIdx.x;
    if (c < OCH) {
        const float inv = 1.f / (float)NPIX;
        float mean = gsum[c] * inv;
        float var = gsq[c] * inv - mean * mean;
        float rstd = rsqrtf(var + 1e-5f);
        float sc = gamma[c] * rstd;
        ss[c] = sc;
        ss[OCH + c] = beta[c] - mean * sc;
    }
}

// ---------------- kernel 4: BN apply + PReLU (bf16 y -> f32 out) ----------------
__global__ __launch_bounds__(256) void apply_bn(const unsigned short* __restrict__ ybuf,
                                                const float* __restrict__ ss,
                                                const float* __restrict__ prelu,
                                                float* __restrict__ out) {
    int i = blockIdx.x * 256 + threadIdx.x;
    int oc = ((i * 8) >> 14) & 63;
    float sc = ss[oc], sh = ss[OCH + oc], pw = prelu[oc];
    ushort8v v8 = ((const ushort8v*)ybuf)[i];
    float4 o0, o1;
    float t;
    t = fmaf(bf2f(v8[0]), sc, sh); o0.x = t >= 0.f ? t : pw * t;
    t = fmaf(bf2f(v8[1]), sc, sh); o0.y = t >= 0.f ? t : pw * t;
    t = fmaf(bf2f(v8[2]), sc, sh); o0.z = t >= 0.f ? t : pw * t;
    t = fmaf(bf2f(v8[3]), sc, sh); o0.w = t >= 0.f ? t : pw * t;
    t = fmaf(bf2f(v8[4]), sc, sh); o1.x = t >= 0.f ? t : pw * t;
    t = fmaf(bf2f(v8[5]), sc, sh); o1.y = t >= 0.f ? t : pw * t;
    t = fmaf(bf2f(v8[6]), sc, sh); o1.z = t >= 0.f ? t : pw * t;
    t = fmaf(bf2f(v8[7]), sc, sh); o1.w = t >= 0.f ? t : pw * t;
    ((float4*)out)[i * 2]     = o0;
    ((float4*)out)[i * 2 + 1] = o1;
}

extern "C" void kernel_launch(void* const* d_in, const int* in_sizes, int n_in,
                              void* d_out, int out_size, void* d_ws, size_t ws_size,
                              hipStream_t stream) {
    const float* x      = (const float*)d_in[0];
    const float* w_off  = (const float*)d_in[1];
    const float* b_off  = (const float*)d_in[2];
    const float* w_def  = (const float*)d_in[3];
    const float* b_def  = (const float*)d_in[4];
    const float* gamma  = (const float*)d_in[5];
    const float* beta   = (const float*)d_in[6];
    const float* prelu  = (const float*)d_in[7];

    float* ws    = (float*)d_ws;
    unsigned short* ybuf = (unsigned short*)(ws + Y_OFF);
    short* wtb   = (short*)(ws + WTB_OFF);
    short* wofb  = (short*)(ws + WOFB_OFF);
    float* stats = ws + STATS_OFF;
    float* gsum  = stats;
    float* gsq   = stats + OCH;
    float* ss    = stats + 2 * OCH;

    // xt (NHWC bf16 x) lives in d_out: dead by the time apply_bn rewrites it.
    unsigned short* xt = (unsigned short*)d_out;

    prep_w<<<216, 256, 0, stream>>>(w_def, w_off, wtb, wofb, stats);
    transpose_x<<<BSZ * HWSZ / 32, 256, 0, stream>>>(x, xt);
    deform_fused<<<BSZ * HH * 2, 256, 0, stream>>>(xt, wofb, b_off, wtb, b_def, ybuf, gsum, gsq);
    finalize_bn<<<1, 64, 0, stream>>>(gsum, gsq, gamma, beta, ss);
    apply_bn<<<(BSZ * OCH * HWSZ) / 8 / 256, 256, 0, stream>>>(ybuf, ss, prelu, (float*)d_out);
}

// Round 17
// 173.593 us; speedup vs baseline: 1.7312x; 1.0018x over previous
//
#include <hip/hip_runtime.h>

#define BSZ 4
#define CIN 64
#define HH 128
#define WW 128
#define OCH 64
#define HWSZ (HH*WW)
#define KK 9
#define NPIX (BSZ*HH*WW)

typedef __attribute__((ext_vector_type(8))) short short8v;
typedef __attribute__((ext_vector_type(8))) unsigned short ushort8v;
typedef __attribute__((ext_vector_type(4))) float float4v;

// ws layout (float slots)
#define Y_OFF     0                                 // ybuf bf16: 2097152 float slots
#define WTB_OFF   2097152                           // 36864 bf16 = 18432 float slots
#define WOFB_OFF  (WTB_OFF + 18432)                 // 32*576 bf16 = 9216 float slots
#define STATS_OFF (WOFB_OFF + 9216)                 // gsum[64] gsq[64]

__device__ __forceinline__ short f2bf(float f) {
    unsigned u = __builtin_bit_cast(unsigned, f);
    unsigned r = (u + 0x7FFFu + ((u >> 16) & 1u)) >> 16;
    return (short)r;
}
__device__ __forceinline__ float bf2f(unsigned short u) {
    return __builtin_bit_cast(float, ((unsigned)u) << 16);
}

// ---------------- kernel 0: prep (transpose + weights + stats zero) ----------------
// blocks 0..2047: NCHW->NHWC bf16 transpose; blocks 2048..2263: weight prep.
__global__ __launch_bounds__(256) void prep(const float* __restrict__ x,
                                            const float* __restrict__ w_def,
                                            const float* __restrict__ w_off,
                                            unsigned short* __restrict__ xt,
                                            short* __restrict__ wtb,
                                            short* __restrict__ wofb,
                                            float* __restrict__ stats) {
    __shared__ float t[64][33];
    const int bid = blockIdx.x;
    const int tid = threadIdx.x;
    if (bid >= 2048) {
        if (bid == 2048 && tid < 128) stats[tid] = 0.f;
        int i = (bid - 2048) * 256 + tid;
        if (i < 36864) {
            int oc = i / 576, rr = i % 576;
            int c = rr / 9, k = rr % 9;
            wtb[(k * OCH + oc) * CIN + c] = f2bf(w_def[i]);
        } else if (i < 36864 + 18432) {
            int j = i - 36864;
            int o = j / 576, rr = j % 576;
            int tap = rr / 64, c = rr % 64;
            wofb[j] = (o < 18) ? f2bf(w_off[(o * 64 + c) * 9 + tap]) : (short)0;
        }
        return;
    }
    const int wg  = (bid & 7) * 256 + (bid >> 3);
    const int gp0 = wg * 32;
    const int b   = gp0 >> 14;
    const int hw0 = gp0 & 16383;
    const float* src = x + b * CIN * HWSZ + hw0;
    #pragma unroll
    for (int pass = 0; pass < 8; ++pass) {
        int c = pass * 8 + (tid >> 5);
        int p = tid & 31;
        t[c][p] = src[c * HWSZ + p];
    }
    __syncthreads();
    unsigned short* dst = xt + (b * HWSZ + hw0) * 64;
    #pragma unroll
    for (int pass = 0; pass < 8; ++pass) {
        int p = pass * 4 + (tid >> 6);
        int c = tid & 63;
        dst[p * 64 + c] = (unsigned short)f2bf(t[c][p]);
    }
}

// ---------------- kernel 1: fused offset(MFMA) + deform(MFMA), 70-col LDS band ----------------
__global__ __launch_bounds__(256, 3) void deform_fused(
    const unsigned short* __restrict__ xt,  // NHWC bf16
    const short* __restrict__ wofb,         // [32][tap][c] bf16
    const float* __restrict__ b_off,
    const short* __restrict__ wtb,          // [k][oc][c] bf16
    const float* __restrict__ b_def,
    unsigned short* __restrict__ ybuf,      // bf16
    float* __restrict__ gsum,
    float* __restrict__ gsq)
{
    __shared__ unsigned short band[6 * 70 * 64];   // 53760 B; reused for epilogue reduction

    const int bid  = blockIdx.x;
    const int r    = (bid & 7) * 128 + (bid >> 3);   // XCD swizzle
    const int tid  = threadIdx.x;
    const int lane = tid & 63;
    const int wv   = tid >> 6;
    const int b    = r >> 8;
    const int rem  = r & 255;
    const int ho   = rem >> 1, half = rem & 1;
    const int l15  = lane & 15;
    const int l4   = lane >> 4;
    const int cbase = l4 * 8;
    const int p    = half * 64 + wv * 16 + l15;   // this lane's pixel
    const int bx0  = half * 64 - 3;               // band col origin (70 cols)

    const unsigned short* xb = xt + b * HWSZ * 64;
    char* bandc = (char*)band;

    // ---- stage band: rows ho-2..ho+3, cols bx0..bx0+69 (granule-XOR swizzled) ----
    #pragma unroll
    for (int i = 0; i < 14; ++i) {
        int G = i * 256 + tid;               // 3360 granules
        if (G < 3360) {
            int g  = G & 7;
            int xs = (G >> 3) % 70;
            int rs = (G >> 3) / 70;
            int row = min(max(ho - 2 + rs, 0), HH - 1);
            int col = min(max(bx0 + xs, 0), WW - 1);
            ushort8v v = *(const ushort8v*)(xb + (row * WW + col) * 64 + g * 8);
            *(ushort8v*)(bandc + ((rs * 70 + xs) << 7) + ((g ^ (xs & 7)) << 4)) = v;
        }
    }
    __syncthreads();

    // ---- phase A: offset conv via MFMA (reads band); och via intra-wave shfl ----
    float och[18];
    {
        float4v offacc0 = (float4v){0.f, 0.f, 0.f, 0.f};
        float4v offacc1 = (float4v){0.f, 0.f, 0.f, 0.f};
        const ushort8v zero8 = {0, 0, 0, 0, 0, 0, 0, 0};
        #pragma unroll
        for (int kk = 0; kk < 18; ++kk) {
            const int tap = kk >> 1;
            const int kh = tap / 3, kw = tap % 3;
            const int yy = ho - 1 + kh;
            const int xx = p - 1 + kw;
            const bool valid = ((unsigned)yy < (unsigned)HH) & ((unsigned)xx < (unsigned)WW);
            ushort8v bo = zero8;
            if (valid) {
                int xs = xx - bx0;                    // in [2,67]
                int q  = l4 + (kk & 1) * 4;
                int adr = (((kh + 1) * 70 + xs) << 7) + ((q ^ (xs & 7)) << 4);
                bo = *(const ushort8v*)(bandc + adr);
            }
            short8v bos = __builtin_bit_cast(short8v, bo);
            short8v af0 = *(const short8v*)(wofb + (l15) * 576 + kk * 32 + cbase);
            short8v af1 = *(const short8v*)(wofb + (16 + l15) * 576 + kk * 32 + cbase);
            offacc0 = __builtin_amdgcn_mfma_f32_16x16x32_bf16(af0, bos, offacc0, 0, 0, 0);
            offacc1 = __builtin_amdgcn_mfma_f32_16x16x32_bf16(af1, bos, offacc1, 0, 0, 0);
        }
        // D layout: col(pixel)=l15, row(off-ch)=l4*4+reg. Pull all 18 rows for my column.
        #pragma unroll
        for (int j = 0; j < 16; ++j)
            och[j] = __shfl(offacc0[j & 3], (j >> 2) * 16 + l15) + b_off[j];
        #pragma unroll
        for (int t2 = 0; t2 < 2; ++t2)
            och[16 + t2] = __shfl(offacc1[t2], l15) + b_off[16 + t2];
    }

    // ---- phase B: deform conv via MFMA (band gathers, global fallback) ----
    float4v acc[4];
    #pragma unroll
    for (int mt = 0; mt < 4; ++mt) acc[mt] = (float4v){0.f, 0.f, 0.f, 0.f};

    #pragma unroll
    for (int k = 0; k < KK; ++k) {
        float dy = och[2 * k];
        float dx = och[2 * k + 1];
        float py = (float)(ho - 1 + (k / 3)) + dy;
        float px = (float)(p - 1 + (k % 3)) + dx;
        float y0f = floorf(py), x0f = floorf(px);
        int y0 = (int)y0f, x0 = (int)x0f;
        float wy1 = py - y0f, wy0 = 1.f - wy1;
        float wx1 = px - x0f, wx0f_ = 1.f - wx1;
        int vy0 = ((unsigned)y0 < (unsigned)HH), vy1 = ((unsigned)(y0 + 1) < (unsigned)HH);
        int vx0 = ((unsigned)x0 < (unsigned)WW), vx1 = ((unsigned)(x0 + 1) < (unsigned)WW);
        float w00 = wy0 * wx0f_ * (float)(vy0 & vx0);
        float w01 = wy0 * wx1  * (float)(vy0 & vx1);
        float w10 = wy1 * wx0f_ * (float)(vy1 & vx0);
        float w11 = wy1 * wx1  * (float)(vy1 & vx1);
        int y0c = min(max(y0, 0), HH - 1), y1c = min(max(y0 + 1, 0), HH - 1);
        int x0c = min(max(x0, 0), WW - 1), x1c = min(max(x0 + 1, 0), WW - 1);

        int sy0 = y0c - (ho - 2), sy1 = y1c - (ho - 2);
        int sx0 = x0c - bx0,      sx1 = x1c - bx0;
        bool inb = (sy0 >= 0) & (sy1 < 6) & (sx0 >= 0) & (sx1 < 70);

        ushort8v g00a, g01a, g10a, g11a, g00b, g01b, g10b, g11b;
        if (__builtin_expect(inb, 1)) {
            const int qa = l4, qb = l4 + 4;
            int a00 = ((sy0 * 70 + sx0) << 7);
            int a01 = ((sy0 * 70 + sx1) << 7);
            int a10 = ((sy1 * 70 + sx0) << 7);
            int a11 = ((sy1 * 70 + sx1) << 7);
            int h0 = (sx0 & 7), h1 = (sx1 & 7);
            g00a = *(const ushort8v*)(bandc + a00 + ((qa ^ h0) << 4));
            g01a = *(const ushort8v*)(bandc + a01 + ((qa ^ h1) << 4));
            g10a = *(const ushort8v*)(bandc + a10 + ((qa ^ h0) << 4));
            g11a = *(const ushort8v*)(bandc + a11 + ((qa ^ h1) << 4));
            g00b = *(const ushort8v*)(bandc + a00 + ((qb ^ h0) << 4));
            g01b = *(const ushort8v*)(bandc + a01 + ((qb ^ h1) << 4));
            g10b = *(const ushort8v*)(bandc + a10 + ((qb ^ h0) << 4));
            g11b = *(const ushort8v*)(bandc + a11 + ((qb ^ h1) << 4));
        } else {
            const unsigned short* p00 = xb + (y0c * WW + x0c) * 64 + cbase;
            const unsigned short* p01 = xb + (y0c * WW + x1c) * 64 + cbase;
            const unsigned short* p10 = xb + (y1c * WW + x0c) * 64 + cbase;
            const unsigned short* p11 = xb + (y1c * WW + x1c) * 64 + cbase;
            g00a = *(const ushort8v*)(p00);      g01a = *(const ushort8v*)(p01);
            g10a = *(const ushort8v*)(p10);      g11a = *(const ushort8v*)(p11);
            g00b = *(const ushort8v*)(p00 + 32); g01b = *(const ushort8v*)(p01 + 32);
            g10b = *(const ushort8v*)(p10 + 32); g11b = *(const ushort8v*)(p11 + 32);
        }

        short8v Bf[2];
        #pragma unroll
        for (int j = 0; j < 8; ++j) {
            float v = bf2f(g00a[j]) * w00 + bf2f(g01a[j]) * w01
                    + bf2f(g10a[j]) * w10 + bf2f(g11a[j]) * w11;
            Bf[0][j] = f2bf(v);
        }
        #pragma unroll
        for (int j = 0; j < 8; ++j) {
            float v = bf2f(g00b[j]) * w00 + bf2f(g01b[j]) * w01
                    + bf2f(g10b[j]) * w10 + bf2f(g11b[j]) * w11;
            Bf[1][j] = f2bf(v);
        }

        const short* wk = wtb + k * OCH * CIN;
        #pragma unroll
        for (int mt = 0; mt < 4; ++mt) {
            const short* wrow = wk + (mt * 16 + l15) * CIN + cbase;
            #pragma unroll
            for (int kc = 0; kc < 2; ++kc) {
                short8v Af = *(const short8v*)(wrow + kc * 32);
                acc[mt] = __builtin_amdgcn_mfma_f32_16x16x32_bf16(Af, Bf[kc], acc[mt], 0, 0, 0);
            }
        }
    }

    // ---- epilogue: bias, y store (bf16), BN partials (band LDS reused) ----
    float lsum[4][4], lsq[4][4];
    const int yrow = ho * WW;
    #pragma unroll
    for (int mt = 0; mt < 4; ++mt) {
        #pragma unroll
        for (int rr = 0; rr < 4; ++rr) {
            const int oc = mt * 16 + l4 * 4 + rr;
            float v = acc[mt][rr] + b_def[oc];
            ybuf[(b * OCH + oc) * HWSZ + yrow + p] = (unsigned short)f2bf(v);
            lsum[mt][rr] = v;
            lsq[mt][rr]  = v * v;
        }
    }
    #pragma unroll
    for (int m = 1; m <= 8; m <<= 1) {
        #pragma unroll
        for (int mt = 0; mt < 4; ++mt)
            #pragma unroll
            for (int rr = 0; rr < 4; ++rr) {
                lsum[mt][rr] += __shfl_xor(lsum[mt][rr], m);
                lsq[mt][rr]  += __shfl_xor(lsq[mt][rr], m);
            }
    }
    __syncthreads();                       // all band reads done; safe to reuse
    float* redp = (float*)bandc;           // [2][4][64] floats = 2 KB
    if (l15 == 0) {
        #pragma unroll
        for (int mt = 0; mt < 4; ++mt)
            #pragma unroll
            for (int rr = 0; rr < 4; ++rr) {
                const int oc = mt * 16 + l4 * 4 + rr;
                redp[(0 * 4 + wv) * 64 + oc] = lsum[mt][rr];
                redp[(1 * 4 + wv) * 64 + oc] = lsq[mt][rr];
            }
    }
    __syncthreads();
    if (tid < 128) {
        const int oc = tid & 63, s = tid >> 6;
        float v = redp[(s * 4 + 0) * 64 + oc] + redp[(s * 4 + 1) * 64 + oc]
                + redp[(s * 4 + 2) * 64 + oc] + redp[(s * 4 + 3) * 64 + oc];
        atomicAdd((s == 0) ? &gsum[oc] : &gsq[oc], v);
    }
}

// ---------------- kernel 2: BN finalize + apply + PReLU (bf16 y -> f32 out) ----------------
__global__ __launch_bounds__(256) void apply_bn(const unsigned short* __restrict__ ybuf,
                                                const float* __restrict__ gsum,
                                                const float* __restrict__ gsq,
                                                const float* __restrict__ gamma,
                                                const float* __restrict__ beta,
                                                const float* __restrict__ prelu,
                                                float* __restrict__ out) {
    int i = blockIdx.x * 256 + threadIdx.x;       // ushort8 group index
    int oc = ((i * 8) >> 14) & 63;                // single oc per block
    const float inv = 1.f / (float)NPIX;
    float mean = gsum[oc] * inv;
    float var  = gsq[oc] * inv - mean * mean;
    float rstd = rsqrtf(var + 1e-5f);
    float sc = gamma[oc] * rstd;
    float sh = beta[oc] - mean * sc;
    float pw = prelu[oc];
    ushort8v v8 = ((const ushort8v*)ybuf)[i];
    float4 o0, o1;
    float t;
    t = fmaf(bf2f(v8[0]), sc, sh); o0.x = t >= 0.f ? t : pw * t;
    t = fmaf(bf2f(v8[1]), sc, sh); o0.y = t >= 0.f ? t : pw * t;
    t = fmaf(bf2f(v8[2]), sc, sh); o0.z = t >= 0.f ? t : pw * t;
    t = fmaf(bf2f(v8[3]), sc, sh); o0.w = t >= 0.f ? t : pw * t;
    t = fmaf(bf2f(v8[4]), sc, sh); o1.x = t >= 0.f ? t : pw * t;
    t = fmaf(bf2f(v8[5]), sc, sh); o1.y = t >= 0.f ? t : pw * t;
    t = fmaf(bf2f(v8[6]), sc, sh); o1.z = t >= 0.f ? t : pw * t;
    t = fmaf(bf2f(v8[7]), sc, sh); o1.w = t >= 0.f ? t : pw * t;
    ((float4*)out)[i * 2]     = o0;
    ((float4*)out)[i * 2 + 1] = o1;
}

extern "C" void kernel_launch(void* const* d_in, const int* in_sizes, int n_in,
                              void* d_out, int out_size, void* d_ws, size_t ws_size,
                              hipStream_t stream) {
    const float* x      = (const float*)d_in[0];
    const float* w_off  = (const float*)d_in[1];
    const float* b_off  = (const float*)d_in[2];
    const float* w_def  = (const float*)d_in[3];
    const float* b_def  = (const float*)d_in[4];
    const float* gamma  = (const float*)d_in[5];
    const float* beta   = (const float*)d_in[6];
    const float* prelu  = (const float*)d_in[7];

    float* ws    = (float*)d_ws;
    unsigned short* ybuf = (unsigned short*)(ws + Y_OFF);
    short* wtb   = (short*)(ws + WTB_OFF);
    short* wofb  = (short*)(ws + WOFB_OFF);
    float* stats = ws + STATS_OFF;
    float* gsum  = stats;
    float* gsq   = stats + OCH;

    // xt (NHWC bf16 x) lives in d_out: dead by the time apply_bn rewrites it.
    unsigned short* xt = (unsigned short*)d_out;

    prep<<<2048 + 216, 256, 0, stream>>>(x, w_def, w_off, xt, wtb, wofb, stats);
    deform_fused<<<BSZ * HH * 2, 256, 0, stream>>>(xt, wofb, b_off, wtb, b_def, ybuf, gsum, gsq);
    apply_bn<<<(BSZ * OCH * HWSZ) / 8 / 256, 256, 0, stream>>>(ybuf, gsum, gsq, gamma, beta, prelu, (float*)d_out);
}